// Round 6
// baseline (676.883 us; speedup 1.0000x reference)
//
#include <hip/hip_runtime.h>

#define NN 100000   // nodes
#define NC 200000   // cells
#define NE 300000   // edges
#define D  128
#define NB 391      // scan blocks = ceil(NN/256)
#define HB 2344     // hist blocks = ceil(2E/256) = ceil(3C/256)
#define ECB 9375    // edge bf16-convert blocks: NE*128/(16*256)

typedef unsigned short u16;
typedef __attribute__((ext_vector_type(8))) short bf16x8;  // 8 bf16 = 4 VGPRs
typedef __attribute__((ext_vector_type(4))) float f32x4;   // MFMA accumulator

__device__ __forceinline__ u16 f2bf(float x) {            // fp32 -> bf16 (RNE)
    unsigned int u = __float_as_uint(x);
    u += 0x7fffu + ((u >> 16) & 1u);
    return (u16)(u >> 16);
}
__device__ __forceinline__ float bf2f(u16 h) {
    return __uint_as_float((unsigned int)h << 16);
}
// packed f32x2 -> bf16x2 (low16 = a, high16 = b); no builtin on gfx950
__device__ __forceinline__ unsigned int cvt_pk_bf16(float a, float b) {
    unsigned int r;
    asm("v_cvt_pk_bf16_f32 %0, %1, %2" : "=v"(r) : "v"(a), "v"(b));
    return r;
}

#define MFMA16(a, b, c) __builtin_amdgcn_mfma_f32_16x16x32_bf16((a), (b), (c), 0, 0, 0)

// ====== histograms + W prepack + (optional) edge_attr bf16 mirror ======
__global__ __launch_bounds__(256) void k_hist_w(const int* __restrict__ ei,
                                                const int* __restrict__ face,
                                                const float* __restrict__ edge_attr,
                                                int* __restrict__ cntA,
                                                int* __restrict__ cntF,
                                                const float* __restrict__ W1,
                                                const float* __restrict__ W2,
                                                u16* __restrict__ w1h, u16* __restrict__ w1l,
                                                u16* __restrict__ w2h, u16* __restrict__ w2l,
                                                u16* __restrict__ eab) {
    int b = blockIdx.x;
    int t = threadIdx.x;
    if (b < HB) {
        int i = b * 256 + t;
        if (i >= 2 * NE) return;
        int tgt = (i < NE) ? ei[NE + i] : ei[i - NE];
        atomicAdd(&cntA[tgt], 1);
    } else if (b < 2 * HB) {
        int i = (b - HB) * 256 + t;
        if (i >= 3 * NC) return;
        atomicAdd(&cntF[face[i]], 1);
    } else if (b < 2 * HB + 24) {
        int tid = (b - 2 * HB) * 256 + t;
        if (tid >= 6144) return;                 // 64 W1 frags + 32 W2 frags, 64 lanes each
        int l = tid & 63;
        int f = tid >> 6;
        const float* W; u16 *oh, *ol; int fi;
        if (f < 64) { W = W1; oh = w1h; ol = w1l; fi = f; }
        else        { W = W2; oh = w2h; ol = w2l; fi = f - 64; }
        int kt = fi >> 3, nt = fi & 7;
        int k0 = kt * 32 + 8 * (l >> 4);
        int n  = nt * 16 + (l & 15);
        #pragma unroll
        for (int i = 0; i < 8; i++) {
            float x = W[(size_t)(k0 + i) * 128 + n];
            u16 h = f2bf(x);
            oh[(size_t)fi * 512 + l * 8 + i] = h;
            ol[(size_t)fi * 512 + l * 8 + i] = f2bf(x - bf2f(h));
        }
    } else {
        // ---- edge_attr -> packed bf16 mirror (16 elems/thread) ----
        size_t base = ((size_t)(b - 2 * HB - 24) * 256 + t) * 16;
        const float4* src = (const float4*)(edge_attr + base);
        uint4 o[2];
        unsigned int* op = (unsigned int*)o;
        #pragma unroll
        for (int i = 0; i < 4; i++) {
            float4 v4 = src[i];
            op[2 * i]     = cvt_pk_bf16(v4.x, v4.y);
            op[2 * i + 1] = cvt_pk_bf16(v4.z, v4.w);
        }
        ((uint4*)(eab + base))[0] = o[0];
        ((uint4*)(eab + base))[1] = o[1];
    }
}

// ================= CSR scan (both arrays in one grid) =================
__global__ __launch_bounds__(256) void k_scan_blocks(const int* __restrict__ cntA,
                                                     const int* __restrict__ cntF,
                                                     int* __restrict__ bsumA,
                                                     int* __restrict__ bsumF) {
    __shared__ int s[256];
    int bb = blockIdx.x;
    bool fa = bb >= NB;
    const int* cnt = fa ? cntF : cntA;
    int* bsum = fa ? bsumF : bsumA;
    int blk = fa ? bb - NB : bb;
    int t = threadIdx.x;
    int i = blk * 256 + t;
    s[t] = (i < NN) ? cnt[i] : 0;
    __syncthreads();
    #pragma unroll
    for (int off = 128; off > 0; off >>= 1) {
        if (t < off) s[t] += s[t + off];
        __syncthreads();
    }
    if (t == 0) bsum[blk] = s[0];
}

__global__ __launch_bounds__(512) void k_scan_top(int* __restrict__ bsumA,
                                                  int* __restrict__ bsumF, int nb) {
    __shared__ int s[512];
    int* bsum = blockIdx.x ? bsumF : bsumA;
    int t = threadIdx.x;
    int v = (t < nb) ? bsum[t] : 0;
    s[t] = v;
    __syncthreads();
    #pragma unroll
    for (int off = 1; off < 512; off <<= 1) {
        int x = (t >= off) ? s[t - off] : 0;
        __syncthreads();
        s[t] += x;
        __syncthreads();
    }
    if (t < nb) bsum[t] = s[t] - v;   // exclusive
}

__global__ __launch_bounds__(256) void k_scan_final(const int* __restrict__ cntA,
                                                    const int* __restrict__ cntF,
                                                    const int* __restrict__ bsumA,
                                                    const int* __restrict__ bsumF,
                                                    int* __restrict__ offA,
                                                    int* __restrict__ offF) {
    __shared__ int s[256];
    int bb = blockIdx.x;
    bool fa = bb >= NB;
    const int* cnt = fa ? cntF : cntA;
    const int* bsum = fa ? bsumF : bsumA;
    int* off_out = fa ? offF : offA;
    int total = fa ? 3 * NC : 2 * NE;
    int blk = fa ? bb - NB : bb;
    int t = threadIdx.x;
    int i = blk * 256 + t;
    int v = (i < NN) ? cnt[i] : 0;
    s[t] = v;
    __syncthreads();
    #pragma unroll
    for (int off = 1; off < 256; off <<= 1) {
        int x = (t >= off) ? s[t - off] : 0;
        __syncthreads();
        s[t] += x;
        __syncthreads();
    }
    if (i < NN) off_out[i] = s[t] - v + bsum[blk];
    if (i == 0) off_out[NN] = total;
}

// ===== fill (edge-row slots, face slots) =====
__global__ __launch_bounds__(256) void k_fill(const int* __restrict__ ei,
                                              const int* __restrict__ face,
                                              const int* __restrict__ offA,
                                              const int* __restrict__ offF,
                                              int* __restrict__ curA,
                                              int* __restrict__ curF,
                                              int* __restrict__ slotsA,
                                              int* __restrict__ slotsF) {
    int b = blockIdx.x;
    int t = threadIdx.x;
    if (b < HB) {
        int i = b * 256 + t;
        if (i >= 2 * NE) return;
        int tgt = (i < NE) ? ei[NE + i] : ei[i - NE];
        int pos = offA[tgt] + atomicAdd(&curA[tgt], 1);
        slotsA[pos] = (i < NE) ? i : i - NE;      // edge row in [0, NE)
    } else {
        int i = (b - HB) * 256 + t;
        if (i >= 3 * NC) return;
        int tgt = face[i];
        int pos = offF[tgt] + atomicAdd(&curF[tgt], 1);
        int c = i; if (c >= NC) c -= NC; if (c >= NC) c -= NC;   // cell id = i mod NC
        slotsF[pos] = c;
    }
}

// helper: load one edge row chunk (2 cols/lane) from fp32 or bf16 mirror
template<int BF>
__device__ __forceinline__ float2 erow(const float* ea, const u16* eb, int row, int lane) {
    if (BF) {
        unsigned int u = ((const unsigned int*)(eb + (size_t)row * D))[lane];
        float2 r; r.x = bf2f((u16)(u & 0xffffu)); r.y = bf2f((u16)(u >> 16));
        return r;
    } else {
        return ((const float2*)(ea + (size_t)row * D))[lane];
    }
}

// ===== fused attention + aggregation: per node, one emb row reused for all slots =====
template<int BF>
__global__ __launch_bounds__(256) void k_agg_att(const float* __restrict__ edge_attr,
                                                 const u16* __restrict__ eab,
                                                 const float* __restrict__ emb,
                                                 const int* __restrict__ offs,
                                                 const int* __restrict__ slots,
                                                 float* __restrict__ na) {
    int n = blockIdx.x * 4 + (threadIdx.x >> 6);
    int lane = threadIdx.x & 63;
    if (n >= NN) return;
    int s0 = offs[n], s1 = offs[n + 1];
    int deg = s1 - s0;
    float2 e = ((const float2*)(emb + (size_t)n * D))[lane];   // reused for every slot
    const float inv_scale = 0.08838834764831845f; // 1/sqrt(128)
    float2 acc = {0.f, 0.f};
    float wsum = 0.f;
    int base = 0;
    while (base < deg) {
        int chunk = deg - base;
        if (chunk > 64) chunk = 64;
        int sl = (lane < chunk) ? slots[s0 + base + lane] : 0;
        int j = 0;
        for (; j + 4 <= chunk; j += 4) {
            int r0 = __shfl(sl, j),     r1 = __shfl(sl, j + 1);
            int r2 = __shfl(sl, j + 2), r3 = __shfl(sl, j + 3);
            float2 a0 = erow<BF>(edge_attr, eab, r0, lane);
            float2 a1 = erow<BF>(edge_attr, eab, r1, lane);
            float2 a2 = erow<BF>(edge_attr, eab, r2, lane);
            float2 a3 = erow<BF>(edge_attr, eab, r3, lane);
            float d0 = a0.x * e.x + a0.y * e.y;
            float d1 = a1.x * e.x + a1.y * e.y;
            float d2 = a2.x * e.x + a2.y * e.y;
            float d3 = a3.x * e.x + a3.y * e.y;
            #pragma unroll
            for (int off = 32; off > 0; off >>= 1) {
                d0 += __shfl_xor(d0, off);
                d1 += __shfl_xor(d1, off);
                d2 += __shfl_xor(d2, off);
                d3 += __shfl_xor(d3, off);
            }
            float w0 = __expf(d0 * inv_scale);
            float w1 = __expf(d1 * inv_scale);
            float w2 = __expf(d2 * inv_scale);
            float w3 = __expf(d3 * inv_scale);
            acc.x += w0 * a0.x + w1 * a1.x + w2 * a2.x + w3 * a3.x;
            acc.y += w0 * a0.y + w1 * a1.y + w2 * a2.y + w3 * a3.y;
            wsum += (w0 + w1) + (w2 + w3);
        }
        for (; j < chunk; ++j) {
            int rr = __shfl(sl, j);
            float2 a = erow<BF>(edge_attr, eab, rr, lane);
            float d = a.x * e.x + a.y * e.y;
            #pragma unroll
            for (int off = 32; off > 0; off >>= 1) d += __shfl_xor(d, off);
            float w = __expf(d * inv_scale);
            acc.x += w * a.x;
            acc.y += w * a.y;
            wsum += w;
        }
        base += chunk;
    }
    float inv = (deg > 0) ? 1.f / wsum : 0.f;
    float2 r; r.x = acc.x * inv; r.y = acc.y * inv;
    ((float2*)(na + (size_t)n * D))[lane] = r;
}

// ===== scatter-mean: register-batched gathers (fp32 or bf16 mirror) =====
template<int BF>
__global__ __launch_bounds__(256) void k_smean_gather(const float* __restrict__ cell_out,
                                                      const u16* __restrict__ cob,
                                                      const int* __restrict__ offs,
                                                      const int* __restrict__ slots,
                                                      float* __restrict__ node_out) {
    int n = blockIdx.x * 4 + (threadIdx.x >> 6);
    int lane = threadIdx.x & 63;
    if (n >= NN) return;
    int s0 = offs[n], s1 = offs[n + 1];
    int deg = s1 - s0;
    float2 acc = {0.f, 0.f};
    int base = 0;
    while (base < deg) {
        int chunk = deg - base;
        if (chunk > 64) chunk = 64;
        int sl = 0;
        if (lane < chunk) sl = slots[s0 + base + lane];
        int j = 0;
        for (; j + 4 <= chunk; j += 4) {
            int c0 = __shfl(sl, j),     c1 = __shfl(sl, j + 1);
            int c2 = __shfl(sl, j + 2), c3 = __shfl(sl, j + 3);
            float2 y0 = erow<BF>(cell_out, cob, c0, lane);
            float2 y1 = erow<BF>(cell_out, cob, c1, lane);
            float2 y2 = erow<BF>(cell_out, cob, c2, lane);
            float2 y3 = erow<BF>(cell_out, cob, c3, lane);
            acc.x += y0.x + y1.x + y2.x + y3.x;
            acc.y += y0.y + y1.y + y2.y + y3.y;
        }
        for (; j < chunk; ++j) {
            int cc = __shfl(sl, j);
            float2 y = erow<BF>(cell_out, cob, cc, lane);
            acc.x += y.x;
            acc.y += y.y;
        }
        base += chunk;
    }
    float inv = deg ? 1.f / (float)deg : 0.f;
    float2 r; r.x = acc.x * inv; r.y = acc.y * inv;
    ((float2*)(node_out + (size_t)n * D))[lane] = r;
}

// ================= fused gather + 2-layer MLP via bf16x3 MFMA =================
// T14 async-stage: na gathers issued before barrier #1, consumed after GEMM1's
// cell-half (96 MFMAs hide the HBM latency).
__device__ __forceinline__ void stage_split(char* lds, int row, int col8, const float* v) {
    unsigned int byte = ((unsigned int)row << 9) + ((unsigned int)col8 << 4);
    byte ^= (unsigned int)(row & 7) << 4;            // G4 swizzle: kill stride-512B conflicts
    uint4 hi, lo;
    unsigned int* hp = (unsigned int*)&hi;
    unsigned int* lp = (unsigned int*)&lo;
    #pragma unroll
    for (int i = 0; i < 4; i++) {
        unsigned int h = cvt_pk_bf16(v[2 * i], v[2 * i + 1]);
        float h0 = __uint_as_float(h << 16);
        float h1 = __uint_as_float(h & 0xffff0000u);
        hp[i] = h;
        lp[i] = cvt_pk_bf16(v[2 * i] - h0, v[2 * i + 1] - h1);
    }
    *(uint4*)(lds + byte)         = hi;              // X-hi: [0, 16K)
    *(uint4*)(lds + 16384 + byte) = lo;              // X-lo: [16K, 32K)
}

__global__ __launch_bounds__(256, 4) void k_mlp(const float* __restrict__ cell_attr,
                                                const float* __restrict__ na,
                                                const int* __restrict__ face,
                                                const u16* __restrict__ w1h,
                                                const u16* __restrict__ w1l,
                                                const u16* __restrict__ w2h,
                                                const u16* __restrict__ w2l,
                                                const float* __restrict__ b1,
                                                const float* __restrict__ b2,
                                                float* __restrict__ out,
                                                u16* __restrict__ cob) {
    __shared__ char lds[32768];
    const int t  = threadIdx.x;
    const int c0 = blockIdx.x * 32;
    const int r  = t >> 3;        // 0..31  (cell row within tile)
    const int q  = t & 7;         // 0..7   (16-col chunk)

    // ---- stage cell_attr half (cols 0..127) ----
    {
        float v[16];
        const float* pa = cell_attr + (size_t)(c0 + r) * D + q * 16;
        #pragma unroll
        for (int i = 0; i < 4; i++) *(float4*)(v + 4 * i) = *(const float4*)(pa + 4 * i);
        stage_split(lds, r, q * 2,     v);
        stage_split(lds, r, q * 2 + 1, v + 8);
    }

    // ---- ISSUE na gathers (not consumed until after GEMM1 first half) ----
    float4 n0[4], n1[4], n2[4];
    {
        const int cid = c0 + r;
        const int f0 = face[cid], f1 = face[NC + cid], f2 = face[2 * NC + cid];
        const float4* p0 = (const float4*)(na + (size_t)f0 * D + q * 16);
        const float4* p1 = (const float4*)(na + (size_t)f1 * D + q * 16);
        const float4* p2 = (const float4*)(na + (size_t)f2 * D + q * 16);
        #pragma unroll
        for (int i = 0; i < 4; i++) { n0[i] = p0[i]; n1[i] = p1[i]; n2[i] = p2[i]; }
    }
    __syncthreads();

    const int w  = t >> 6;           // wave 0..3 -> n-quarter
    const int l  = t & 63;
    const int lr = l & 15;           // A row / B-C col within tile
    const int lg = l >> 4;           // k group (8 contiguous k)
    const unsigned int swz = (unsigned int)(lr & 7) << 4;
    const size_t wl8 = (size_t)l * 8;
    const f32x4 z4 = {0.f, 0.f, 0.f, 0.f};
    f32x4 acc[2][2] = {{z4, z4}, {z4, z4}};          // [row-tile][n-tile]

    const unsigned int abase1 = ((unsigned int)lr << 9) + ((unsigned int)lg << 4);
    const u16* pW1h = w1h + (size_t)(w * 2) * 512 + wl8;
    const u16* pW1l = w1l + (size_t)(w * 2) * 512 + wl8;
    auto gemm1 = [&](int ktb, int kte) {
        #pragma unroll 2
        for (int kt = ktb; kt < kte; ++kt) {
            unsigned int ab = (abase1 + (unsigned int)kt * 64) ^ swz;
            bf16x8 aH0 = *(const bf16x8*)(lds + ab);
            bf16x8 aL0 = *(const bf16x8*)(lds + 16384 + ab);
            bf16x8 aH1 = *(const bf16x8*)(lds + ab + 8192);          // rows 16..31
            bf16x8 aL1 = *(const bf16x8*)(lds + 16384 + ab + 8192);
            #pragma unroll
            for (int jn = 0; jn < 2; ++jn) {
                size_t fo = (size_t)(kt * 8 + jn) * 512;
                bf16x8 bH = *(const bf16x8*)(pW1h + fo);
                bf16x8 bL = *(const bf16x8*)(pW1l + fo);
                acc[0][jn] = MFMA16(aH0, bL, acc[0][jn]);
                acc[0][jn] = MFMA16(aL0, bH, acc[0][jn]);
                acc[0][jn] = MFMA16(aH0, bH, acc[0][jn]);
                acc[1][jn] = MFMA16(aH1, bL, acc[1][jn]);
                acc[1][jn] = MFMA16(aL1, bH, acc[1][jn]);
                acc[1][jn] = MFMA16(aH1, bH, acc[1][jn]);
            }
        }
    };

    gemm1(0, 4);      // cell_attr k-half; na loads still in flight

    // ---- consume na loads: mean-of-3, stage cols 128..255 ----
    {
        float v[16];
        const float third = 1.f / 3.f;
        #pragma unroll
        for (int i = 0; i < 4; i++) {
            v[4 * i + 0] = (n0[i].x + n1[i].x + n2[i].x) * third;
            v[4 * i + 1] = (n0[i].y + n1[i].y + n2[i].y) * third;
            v[4 * i + 2] = (n0[i].z + n1[i].z + n2[i].z) * third;
            v[4 * i + 3] = (n0[i].w + n1[i].w + n2[i].w) * third;
        }
        stage_split(lds, r, 16 + q * 2, v);
        stage_split(lds, r, 17 + q * 2, v + 8);
    }
    __syncthreads();

    gemm1(4, 8);      // na k-half

    __syncthreads();   // all waves done reading X before H overwrites it

    // ---- bias + relu, re-split H (32x128) into LDS (reuses X-hi region) ----
    {
        const int col0 = w * 32 + lr;          // jn = 0
        const int col1 = col0 + 16;            // jn = 1
        const float bb0 = b1[col0];
        const float bb1 = b1[col1];
        #pragma unroll
        for (int rt = 0; rt < 2; ++rt) {
            #pragma unroll
            for (int rr = 0; rr < 4; ++rr) {
                int row = rt * 16 + lg * 4 + rr;      // C/D: row = 4*(lane>>4)+reg
                float h0 = fmaxf(acc[rt][0][rr] + bb0, 0.f);
                float h1 = fmaxf(acc[rt][1][rr] + bb1, 0.f);
                unsigned int ph = cvt_pk_bf16(h0, h1);
                float f0 = __uint_as_float(ph << 16);
                float f1 = __uint_as_float(ph & 0xffff0000u);
                unsigned int pl = cvt_pk_bf16(h0 - f0, h1 - f1);
                unsigned int swzr = (unsigned int)(row & 7) << 4;
                unsigned int b0 = (((unsigned int)row << 8) + ((unsigned int)col0 << 1)) ^ swzr;
                unsigned int bcol1 = (((unsigned int)row << 8) + ((unsigned int)col1 << 1)) ^ swzr;
                *(u16*)(lds + b0)            = (u16)ph;       // H-hi: [0, 8K)
                *(u16*)(lds + bcol1)         = (u16)(ph >> 16);
                *(u16*)(lds + 8192 + b0)     = (u16)pl;       // H-lo: [8K, 16K)
                *(u16*)(lds + 8192 + bcol1)  = (u16)(pl >> 16);
            }
        }
    }
    __syncthreads();

    // ---- GEMM2: H (32x128) @ W2 (128x128), bf16x3 ----
    f32x4 acc2[2][2] = {{z4, z4}, {z4, z4}};
    {
        const unsigned int abase = ((unsigned int)lr << 8) + ((unsigned int)lg << 4);
        const u16* pW2h = w2h + (size_t)(w * 2) * 512 + wl8;
        const u16* pW2l = w2l + (size_t)(w * 2) * 512 + wl8;
        #pragma unroll 2
        for (int kt = 0; kt < 4; ++kt) {
            unsigned int ab = (abase + (unsigned int)kt * 64) ^ swz;
            bf16x8 aH0 = *(const bf16x8*)(lds + ab);
            bf16x8 aL0 = *(const bf16x8*)(lds + 8192 + ab);
            bf16x8 aH1 = *(const bf16x8*)(lds + ab + 4096);          // rows 16..31
            bf16x8 aL1 = *(const bf16x8*)(lds + 8192 + ab + 4096);
            #pragma unroll
            for (int jn = 0; jn < 2; ++jn) {
                size_t fo = (size_t)(kt * 8 + jn) * 512;
                bf16x8 bH = *(const bf16x8*)(pW2h + fo);
                bf16x8 bL = *(const bf16x8*)(pW2l + fo);
                acc2[0][jn] = MFMA16(aH0, bL, acc2[0][jn]);
                acc2[0][jn] = MFMA16(aL0, bH, acc2[0][jn]);
                acc2[0][jn] = MFMA16(aH0, bH, acc2[0][jn]);
                acc2[1][jn] = MFMA16(aH1, bL, acc2[1][jn]);
                acc2[1][jn] = MFMA16(aL1, bH, acc2[1][jn]);
                acc2[1][jn] = MFMA16(aH1, bH, acc2[1][jn]);
            }
        }
    }

    // ---- bias + store (fp32 out, optional bf16 mirror for smean) ----
    #pragma unroll
    for (int jn = 0; jn < 2; ++jn) {
        int col = w * 32 + jn * 16 + lr;
        float bb = b2[col];
        #pragma unroll
        for (int rt = 0; rt < 2; ++rt) {
            #pragma unroll
            for (int rr = 0; rr < 4; ++rr) {
                int row = c0 + rt * 16 + lg * 4 + rr;
                float y = acc2[rt][jn][rr] + bb;
                out[(size_t)row * D + col] = y;
                if (cob) cob[(size_t)row * D + col] = f2bf(y);
            }
        }
    }
}

extern "C" void kernel_launch(void* const* d_in, const int* in_sizes, int n_in,
                              void* d_out, int out_size, void* d_ws, size_t ws_size,
                              hipStream_t stream) {
    (void)in_sizes; (void)n_in; (void)out_size;
    const float* cell_attr = (const float*)d_in[0];
    const float* edge_attr = (const float*)d_in[1];
    const float* emb       = (const float*)d_in[2];
    const int*   ei        = (const int*)d_in[3];
    const int*   face      = (const int*)d_in[4];
    const float* W1        = (const float*)d_in[5];
    const float* b1        = (const float*)d_in[6];
    const float* W2        = (const float*)d_in[7];
    const float* b2        = (const float*)d_in[8];

    float* out_cell = (float*)d_out;                    // [C*D]
    float* out_node = out_cell + (size_t)NC * D;        // [N*D] (node_agg scratch, then final)

    // ws layout (4B units) — zeroed arrays first
    int*   cntA   = (int*)d_ws;                   // [N]
    int*   cntF   = cntA + NN;                    // [N]
    int*   curA   = cntF + NN;                    // [N]
    int*   curF   = curA + NN;                    // [N]
    int*   offA   = curF + NN;                    // [N+1]
    int*   offF   = offA + NN + 1;                // [N+1]
    int*   bsumA  = offF + NN + 1;                // [512]
    int*   bsumF  = bsumA + 512;                  // [512]
    int*   slotsA = bsumF + 512;                  // [2E]
    int*   slotsF = slotsA + 2 * NE;              // [3C]
    // W fragment arrays (16B-aligned): ~0.4 MB
    u16* w1h = (u16*)(((uintptr_t)(slotsF + 3 * NC) + 15) & ~(uintptr_t)15);
    u16* w1l = w1h + 64 * 512;
    u16* w2h = w1l + 64 * 512;                    // 32 frags * 512 u16
    u16* w2l = w2h + 32 * 512;
    // optional bf16 mirrors (tiered by ws_size)
    u16* cob = (u16*)(((uintptr_t)(w2l + 32 * 512) + 255) & ~(uintptr_t)255);  // [C*D]
    u16* eab = (u16*)(((uintptr_t)(cob + (size_t)NC * D) + 255) & ~(uintptr_t)255); // [E*D]
    const char* ws_end = (const char*)d_ws + ws_size;
    bool has_cob = ((const char*)(cob + (size_t)NC * D) <= ws_end);
    bool has_eab = ((const char*)(eab + (size_t)NE * D) <= ws_end);

    hipMemsetAsync(d_ws, 0, (size_t)4 * NN * 4, stream);   // cntA, cntF, curA, curF

    k_hist_w<<<2 * HB + 24 + (has_eab ? ECB : 0), 256, 0, stream>>>(
        ei, face, edge_attr, cntA, cntF, W1, W2, w1h, w1l, w2h, w2l, eab);

    k_scan_blocks<<<2 * NB, 256, 0, stream>>>(cntA, cntF, bsumA, bsumF);
    k_scan_top   <<<2, 512, 0, stream>>>(bsumA, bsumF, NB);
    k_scan_final <<<2 * NB, 256, 0, stream>>>(cntA, cntF, bsumA, bsumF, offA, offF);

    k_fill<<<2 * HB, 256, 0, stream>>>(ei, face, offA, offF, curA, curF, slotsA, slotsF);

    if (has_eab)
        k_agg_att<1><<<(NN + 3) / 4, 256, 0, stream>>>(edge_attr, eab, emb, offA, slotsA, out_node);
    else
        k_agg_att<0><<<(NN + 3) / 4, 256, 0, stream>>>(edge_attr, eab, emb, offA, slotsA, out_node);

    k_mlp<<<NC / 32, 256, 0, stream>>>(cell_attr, out_node, face,
                                       w1h, w1l, w2h, w2l, b1, b2, out_cell,
                                       has_cob ? cob : (u16*)nullptr);

    if (has_cob)
        k_smean_gather<1><<<(NN + 3) / 4, 256, 0, stream>>>(out_cell, cob, offF, slotsF, out_node);
    else
        k_smean_gather<0><<<(NN + 3) / 4, 256, 0, stream>>>(out_cell, cob, offF, slotsF, out_node);
}